// Round 15
// baseline (291.019 us; speedup 1.0000x reference)
//
#include <hip/hip_runtime.h>
#include <hip/hip_bf16.h>
#include <math.h>

#define T_TOK 1024
#define HDIM  2048
#define NEXP  8
#define IDIM  1408
#define ISH   2816
#define ROW_CAP 3072
#define ROWS_ALL 4096
#define MOE_TILES 24
#define NT_TOT 32
#define ATILE (128*64)

typedef __attribute__((ext_vector_type(8))) short bf16x8;
typedef __attribute__((ext_vector_type(4))) float f32x4;

static __device__ __forceinline__ unsigned short f2bf(float f) {
  __hip_bfloat16 h = __float2bfloat16(f);   // RTNE
  return __builtin_bit_cast(unsigned short, h);
}

#define PIPE_WAIT(N) do { \
    asm volatile("s_waitcnt vmcnt(" #N ")" ::: "memory"); \
    __builtin_amdgcn_s_barrier(); \
    __builtin_amdgcn_sched_barrier(0); \
  } while (0)

#define RAW_BAR() do { \
    __builtin_amdgcn_s_barrier(); \
    __builtin_amdgcn_sched_barrier(0); \
  } while (0)

// ---------------- router ----------------
__global__ __launch_bounds__(256) void router_kernel(
    const float* __restrict__ x, const float* __restrict__ rw,
    float* __restrict__ logits_out, int* __restrict__ selk, float* __restrict__ cwk)
{
  int t = blockIdx.x;
  int tid = threadIdx.x;
  float part[NEXP];
  const float* xr = x + (size_t)t * HDIM + tid * 8;
  float4 xa = *reinterpret_cast<const float4*>(xr);
  float4 xb = *reinterpret_cast<const float4*>(xr + 4);
  for (int e = 0; e < NEXP; ++e) {
    const float* wp = rw + (size_t)e * HDIM + tid * 8;
    float4 wa = *reinterpret_cast<const float4*>(wp);
    float4 wb = *reinterpret_cast<const float4*>(wp + 4);
    part[e] = xa.x*wa.x + xa.y*wa.y + xa.z*wa.z + xa.w*wa.w
            + xb.x*wb.x + xb.y*wb.y + xb.z*wb.z + xb.w*wb.w;
  }
  for (int e = 0; e < NEXP; ++e)
    for (int off = 32; off; off >>= 1)
      part[e] += __shfl_xor(part[e], off, 64);
  __shared__ float sums[4][NEXP];
  int wid = tid >> 6, lane = tid & 63;
  if (lane == 0) for (int e = 0; e < NEXP; ++e) sums[wid][e] = part[e];
  __syncthreads();
  if (tid == 0) {
    float lg[NEXP];
    for (int e = 0; e < NEXP; ++e) lg[e] = sums[0][e] + sums[1][e] + sums[2][e] + sums[3][e];
    float mx = lg[0];
    for (int e = 1; e < NEXP; ++e) mx = fmaxf(mx, lg[e]);
    float p[NEXP], s = 0.f;
    for (int e = 0; e < NEXP; ++e) { p[e] = expf(lg[e] - mx); s += p[e]; }
    for (int e = 0; e < NEXP; ++e) p[e] /= s;
    int i1 = 0;
    for (int e = 1; e < NEXP; ++e) if (lg[e] > lg[i1]) i1 = e;
    int i2 = -1;
    for (int e = 0; e < NEXP; ++e) { if (e == i1) continue; if (i2 < 0 || lg[e] > lg[i2]) i2 = e; }
    float denom = p[i1] + p[i2] + 1e-6f;
    selk[t*2] = i1; selk[t*2+1] = i2;
    cwk[t*2] = p[i1] / denom; cwk[t*2+1] = p[i2] / denom;
    for (int e = 0; e < NEXP; ++e) logits_out[t * NEXP + e] = lg[e];
  }
}

// ---------------- plan ----------------
__global__ __launch_bounds__(512) void plan_kernel(
    const int* __restrict__ selk, const float* __restrict__ cwk,
    int* __restrict__ rowidx, int* __restrict__ tok_of_row,
    float* __restrict__ rowwgt, int* __restrict__ tile_tab)
{
  __shared__ int cnt[NEXP];
  __shared__ int seg[NEXP];
  int tid = threadIdx.x;
  int w = tid >> 6, lane = tid & 63;
  for (int i = tid; i < ROW_CAP; i += 512) { tok_of_row[i] = -1; rowwgt[i] = 0.f; }
  for (int i = tid; i < T_TOK; i += 512) { tok_of_row[ROW_CAP + i] = i; rowwgt[ROW_CAP + i] = 1.f; }
  int total = 0;
  for (int base = 0; base < 2 * T_TOK; base += 64) {
    unsigned long long m = __ballot(selk[base + lane] == w);
    total += __popcll(m);
  }
  if (lane == 0) cnt[w] = total;
  __syncthreads();
  if (tid == 0) {
    int s = 0;
    for (int e = 0; e < NEXP; ++e) { seg[e] = s; s += (cnt[e] + 127) & ~127; }
  }
  __syncthreads();
  int run = seg[w];
  for (int base = 0; base < 2 * T_TOK; base += 64) {
    int i = base + lane;
    bool f = selk[i] == w;
    unsigned long long m = __ballot(f);
    if (f) {
      int r = run + __popcll(m & ((1ull << lane) - 1ull));
      rowidx[i] = r;
      tok_of_row[r] = i >> 1;
      rowwgt[r] = cwk[i];
    }
    run += __popcll(m);
  }
  __syncthreads();
  if (tid < NT_TOT) {
    int e = -1, valid = 0;
    if (tid < MOE_TILES) {
      int base = tid * 128;
      for (int k = 0; k < NEXP; ++k) {
        int s0 = seg[k], s1 = s0 + ((cnt[k] + 127) & ~127);
        if (base >= s0 && base < s1) {
          e = k;
          valid = cnt[k] - (base - s0);
          if (valid > 128) valid = 128;
          if (valid < 0) valid = 0;
        }
      }
    } else { e = 0; valid = 128; }
    tile_tab[tid*2] = e;
    tile_tab[tid*2+1] = valid;
  }
}

// ---- cvt one 2048-float row, write bf16 to dst row ----
static __device__ __forceinline__ void cvt_row(
    const float* __restrict__ src, unsigned short* __restrict__ dst, int tid)
{
  size_t idx = (size_t)tid * 8;
  float4 va = *reinterpret_cast<const float4*>(src + idx);
  float4 vb = *reinterpret_cast<const float4*>(src + idx + 4);
  union { unsigned short us[8]; uint4 q; } p;
  p.us[0]=f2bf(va.x); p.us[1]=f2bf(va.y); p.us[2]=f2bf(va.z); p.us[3]=f2bf(va.w);
  p.us[4]=f2bf(vb.x); p.us[5]=f2bf(vb.y); p.us[6]=f2bf(vb.z); p.us[7]=f2bf(vb.w);
  *reinterpret_cast<uint4*>(dst + idx) = p.q;
}

// ---------------- prep: gather (blocks 0..4095) + gate/up interleave-cvt (rest) ----------------
__global__ __launch_bounds__(256) void prep_kernel(
    const float* __restrict__ x, const int* __restrict__ tok_of_row,
    unsigned short* __restrict__ xg,
    const float* __restrict__ wg, const float* __restrict__ wu,
    const float* __restrict__ sg, const float* __restrict__ su,
    unsigned short* __restrict__ dmoe, unsigned short* __restrict__ dsh)
{
  int blk = blockIdx.x;
  int tid = threadIdx.x;
  if (blk < ROWS_ALL) {
    int tok = tok_of_row[blk];
    unsigned short* dst = xg + (size_t)blk * HDIM + tid * 8;
    union { unsigned short us[8]; uint4 q; } p;
    if (tok < 0) {
      p.q = uint4{0, 0, 0, 0};
    } else {
      const float* src = x + (size_t)tok * HDIM + tid * 8;
      float4 a = *reinterpret_cast<const float4*>(src);
      float4 b = *reinterpret_cast<const float4*>(src + 4);
      p.us[0]=f2bf(a.x); p.us[1]=f2bf(a.y); p.us[2]=f2bf(a.z); p.us[3]=f2bf(a.w);
      p.us[4]=f2bf(b.x); p.us[5]=f2bf(b.y); p.us[6]=f2bf(b.z); p.us[7]=f2bf(b.w);
    }
    *reinterpret_cast<uint4*>(dst) = p.q;
    return;
  }
  int b = blk - ROWS_ALL;
  const float* src; unsigned short* dst; size_t drow;
  if (b < NEXP * IDIM) {
    int e = b / IDIM, i = b - e * IDIM;
    src = wg + (size_t)b * HDIM; dst = dmoe;
    drow = (size_t)e * 2 * IDIM + ((i >> 4) << 5) + (i & 15);
  } else if (b < 2 * NEXP * IDIM) {
    int bb = b - NEXP * IDIM;
    int e = bb / IDIM, i = bb - e * IDIM;
    src = wu + (size_t)bb * HDIM; dst = dmoe;
    drow = (size_t)e * 2 * IDIM + ((i >> 4) << 5) + 16 + (i & 15);
  } else if (b < 2 * NEXP * IDIM + ISH) {
    int i = b - 2 * NEXP * IDIM;
    src = sg + (size_t)i * HDIM; dst = dsh;
    drow = ((size_t)(i >> 4) << 5) + (i & 15);
  } else {
    int i = b - 2 * NEXP * IDIM - ISH;
    src = su + (size_t)i * HDIM; dst = dsh;
    drow = ((size_t)(i >> 4) << 5) + 16 + (i & 15);
  }
  cvt_row(src, dst + drow * HDIM, tid);
}

// ---- tile stage: 128x64 bf16 via global_load_lds, 8 waves, XOR-8 source swizzle ----
static __device__ __forceinline__ void stage_t(
    const unsigned short* __restrict__ base, size_t ld, int k0,
    unsigned short* Ls, int wid, int lane)
{
  #pragma unroll
  for (int j = 0; j < 2; ++j) {
    int row = j * 64 + wid * 8 + (lane >> 3);
    int col = ((lane & 7) ^ (row & 7)) << 3;
    const unsigned short* src = base + (size_t)row * ld + k0 + col;
    unsigned short* dst = &Ls[(j * 64 + wid * 8) * 64];   // wave-uniform
    __builtin_amdgcn_global_load_lds(
        (const __attribute__((address_space(1))) void*)src,
        (__attribute__((address_space(3))) void*)dst, 16, 0, 0);
  }
}

// ---- fp32 B stage: 64 x 64 fp32 tile via glds, 16B-chunk XOR-16 source swizzle ----
// LDS row = 64 floats (256B, 16 chunks of 16B). LDS chunk c of row r holds source
// chunk (c ^ (r&15)). Write: linear dst, pre-swizzled source (rule #21 involution).
static __device__ __forceinline__ void stage_bf(
    const float* __restrict__ bbase, size_t ldb, int k0,
    float* Bf, int wid, int lane)
{
  #pragma unroll
  for (int j = 0; j < 2; ++j) {
    int r = (wid * 2 + j) * 4 + (lane >> 4);
    int c = lane & 15;
    const float* src = bbase + (size_t)r * ldb + k0 + ((c ^ (r & 15)) << 2);
    float* dst = &Bf[(size_t)((wid * 2 + j) * 4) * 64];   // wave-uniform
    __builtin_amdgcn_global_load_lds(
        (const __attribute__((address_space(1))) void*)src,
        (__attribute__((address_space(3))) void*)dst, 16, 0, 0);
  }
}

// ---- read fp32 B-fragment (row brow, 32B k-chunk s_log) from swizzled LDS -> bf16x8 ----
static __device__ __forceinline__ bf16x8 ldbf_frag(
    const float* __restrict__ Bf, int brow, int s_log)
{
  int x = brow & 15;
  int c0 = (s_log << 1) ^ x;
  int c1 = ((s_log << 1) | 1) ^ x;
  float4 q0 = *reinterpret_cast<const float4*>(Bf + (size_t)brow * 64 + (c0 << 2));
  float4 q1 = *reinterpret_cast<const float4*>(Bf + (size_t)brow * 64 + (c1 << 2));
  union { unsigned short us[8]; bf16x8 v; } r;
  r.us[0]=f2bf(q0.x); r.us[1]=f2bf(q0.y); r.us[2]=f2bf(q0.z); r.us[3]=f2bf(q0.w);
  r.us[4]=f2bf(q1.x); r.us[5]=f2bf(q1.y); r.us[6]=f2bf(q1.z); r.us[7]=f2bf(q1.w);
  return r.v;
}

// ---------------- gate+up SwiGLU GEMM: interleaved bf16 B, dbuf + counted vmcnt ----------------
__global__ __launch_bounds__(512) void gu_kernel(
    const unsigned short* __restrict__ xg,
    const unsigned short* __restrict__ wgub, const unsigned short* __restrict__ swgub,
    const float* __restrict__ rowwgt, const int* __restrict__ tile_tab,
    unsigned short* __restrict__ hg, unsigned short* __restrict__ hsh)
{
  // packed linear grid 880 = 8*110, mt-fastest + XCD chunk swizzle
  int bid = blockIdx.x;
  int lb = (bid & 7) * 110 + (bid >> 3);
  int mt, nt;
  if (lb < MOE_TILES * 22) { mt = lb % MOE_TILES; nt = lb / MOE_TILES; }
  else { int s = lb - MOE_TILES * 22; mt = MOE_TILES + (s & 7); nt = s >> 3; }

  int e = tile_tab[mt*2], valid = tile_tab[mt*2+1];
  if (valid <= 0) return;
  bool sh = mt >= MOE_TILES;
  int m0 = mt * 128;
  const unsigned short* wb; unsigned short* hout; int ldo;
  if (sh) { wb = swgub; hout = hsh + (size_t)(m0 - ROW_CAP) * ISH; ldo = ISH; }
  else {
    wb = wgub + (size_t)e * 2 * IDIM * HDIM;
    hout = hg + (size_t)m0 * IDIM; ldo = IDIM;
  }

  __shared__ unsigned short As[2 * ATILE];   // 32 KB
  __shared__ unsigned short Bs[2 * ATILE];   // 32 KB

  int tid = threadIdx.x, wid = tid >> 6, lane = tid & 63;
  int wr = wid >> 2, wc = wid & 3;
  int fr = lane & 15, fq = lane >> 4, fq8 = fq << 3;

  f32x4 acc[4][2] = {{}};                   // [m][0]=gate, [m][1]=up

  const unsigned short* abase = xg + (size_t)m0 * HDIM;
  const unsigned short* bbase = wb + (size_t)(nt * 128) * HDIM;

  stage_t(abase, HDIM, 0, As, wid, lane);
  stage_t(bbase, HDIM, 0, Bs, wid, lane);

  const int NK = HDIM / 64;   // 32
  for (int t = 0; t < NK; ++t) {
    int cur = t & 1;
    if (t + 1 < NK) {
      stage_t(abase, HDIM, (t + 1) * 64, As + (cur ^ 1) * ATILE, wid, lane);
      stage_t(bbase, HDIM, (t + 1) * 64, Bs + (cur ^ 1) * ATILE, wid, lane);
      PIPE_WAIT(4);
    } else {
      PIPE_WAIT(0);
    }
    const unsigned short* Ab = As + cur * ATILE;
    const unsigned short* Bb = Bs + cur * ATILE;
    #pragma unroll
    for (int kk = 0; kk < 64; kk += 32) {
      bf16x8 a[4], b[2];
      #pragma unroll
      for (int m = 0; m < 4; ++m) {
        int row = wr * 64 + m * 16 + fr;
        a[m] = *reinterpret_cast<const bf16x8*>(&Ab[row * 64 + ((kk + fq8) ^ ((row & 7) << 3))]);
      }
      #pragma unroll
      for (int n = 0; n < 2; ++n) {
        int brow = wc * 32 + n * 16 + fr;
        b[n] = *reinterpret_cast<const bf16x8*>(&Bb[brow * 64 + ((kk + fq8) ^ ((brow & 7) << 3))]);
      }
      #pragma unroll
      for (int m = 0; m < 4; ++m)
        #pragma unroll
        for (int n = 0; n < 2; ++n)
          acc[m][n] = __builtin_amdgcn_mfma_f32_16x16x32_bf16(a[m], b[n], acc[m][n], 0, 0, 0);
    }
    RAW_BAR();
  }

  int icol = nt * 64 + wc * 16 + fr;
  #pragma unroll
  for (int m = 0; m < 4; ++m)
    #pragma unroll
    for (int j = 0; j < 4; ++j) {
      int grow = wr * 64 + m * 16 + fq * 4 + j;
      float wv = rowwgt[m0 + grow];
      float g = acc[m][0][j], u = acc[m][1][j];
      float hv = g / (1.f + __expf(-g)) * u * wv;
      hout[(size_t)grow * ldo + icol] = f2bf(hv);
    }
}

// ---------------- down-proj GEMM: direct fp32 B, dbuf + counted vmcnt ----------------
// BM=128, BN=64, BK=64.  A bf16 dbuf (32 KB) + B fp32 dbuf (32 KB) = 64 KB.
__global__ __launch_bounds__(512) void dn_kernel(
    const unsigned short* __restrict__ hg, const unsigned short* __restrict__ hsh,
    const float* __restrict__ w_down, const float* __restrict__ sw_down,
    const int* __restrict__ tile_tab,
    float* __restrict__ ydn, float* __restrict__ outf)
{
  // packed linear grid 1024 = 8*128, mt-fastest + XCD chunk swizzle
  int bid = blockIdx.x;
  int lb = (bid & 7) * 128 + (bid >> 3);
  int mt, nt;
  if (lb < MOE_TILES * 32) { mt = lb % MOE_TILES; nt = lb / MOE_TILES; }   // MoE nt 0..31
  else { int s = lb - MOE_TILES * 32; mt = MOE_TILES + (s & 7); nt = s >> 3; }  // shared nt 0..31

  int e = tile_tab[mt*2], valid = tile_tab[mt*2+1];
  if (valid <= 0) return;
  bool sh = mt >= MOE_TILES;
  int m0 = mt * 128, n0 = nt * 64;
  const unsigned short* abase; const float* bbase; int K; float* obase;
  if (sh) { abase = hsh + (size_t)(m0 - ROW_CAP) * ISH; K = ISH; bbase = sw_down; obase = outf + (size_t)(m0 - ROW_CAP) * HDIM; }
  else { abase = hg + (size_t)m0 * IDIM; K = IDIM; bbase = w_down + (size_t)e * HDIM * IDIM; obase = ydn + (size_t)m0 * HDIM; }

  __shared__ unsigned short As[2 * ATILE];   // 32 KB
  __shared__ float Bf[2 * 64 * 64];          // 32 KB fp32

  int tid = threadIdx.x, wid = tid >> 6, lane = tid & 63;
  int wr = wid >> 2, wc = wid & 3;           // 2M x 4N waves, 64x16 out per wave
  int fr = lane & 15, fq = lane >> 4, fq8 = fq << 3;

  f32x4 acc[4] = {};

  const float* bb = bbase + (size_t)n0 * K;

  stage_t(abase, K, 0, As, wid, lane);
  stage_bf(bb,   K, 0, Bf, wid, lane);

  const int NK = K / 64;   // 22 or 44
  for (int t = 0; t < NK; ++t) {
    int cur = t & 1;
    if (t + 1 < NK) {
      stage_t(abase, K, (t + 1) * 64, As + (cur ^ 1) * ATILE, wid, lane);
      stage_bf(bb,   K, (t + 1) * 64, Bf + (cur ^ 1) * 64 * 64, wid, lane);
      PIPE_WAIT(4);
    } else {
      PIPE_WAIT(0);
    }
    const unsigned short* Ab = As + cur * ATILE;
    const float* Bb = Bf + cur * 64 * 64;
    #pragma unroll
    for (int kk = 0; kk < 2; ++kk) {
      bf16x8 a[4];
      #pragma unroll
      for (int m = 0; m < 4; ++m) {
        int row = wr * 64 + m * 16 + fr;
        a[m] = *reinterpret_cast<const bf16x8*>(
            &Ab[row * 64 + ((kk * 32 + fq8) ^ ((row & 7) << 3))]);
      }
      bf16x8 b = ldbf_frag(Bb, wc * 16 + fr, kk * 4 + fq);
      #pragma unroll
      for (int m = 0; m < 4; ++m)
        acc[m] = __builtin_amdgcn_mfma_f32_16x16x32_bf16(a[m], b, acc[m], 0, 0, 0);
    }
    RAW_BAR();
  }
  #pragma unroll
  for (int m = 0; m < 4; ++m)
    #pragma unroll
    for (int j = 0; j < 4; ++j) {
      int grow = wr * 64 + m * 16 + fq * 4 + j;
      obase[(size_t)grow * HDIM + n0 + wc * 16 + fr] = acc[m][j];
    }
}

// ---------------- combine ----------------
__global__ __launch_bounds__(256) void combine_kernel(
    const float* __restrict__ ydn, const int* __restrict__ rowidx,
    float* __restrict__ outf)
{
  int t = blockIdx.x;
  int c = threadIdx.x * 8;
  int r0 = rowidx[t*2], r1 = rowidx[t*2+1];
  const float4* a0 = reinterpret_cast<const float4*>(ydn + (size_t)r0 * HDIM + c);
  const float4* a1 = reinterpret_cast<const float4*>(ydn + (size_t)r1 * HDIM + c);
  float4* o = reinterpret_cast<float4*>(outf + (size_t)t * HDIM + c);
  float4 x0 = a0[0], x1 = a0[1], y0 = a1[0], y1 = a1[1];
  float4 o0 = o[0], o1 = o[1];
  o0.x += x0.x + y0.x; o0.y += x0.y + y0.y; o0.z += x0.z + y0.z; o0.w += x0.w + y0.w;
  o1.x += x1.x + y1.x; o1.y += x1.y + y1.y; o1.z += x1.z + y1.z; o1.w += x1.w + y1.w;
  o[0] = o0; o[1] = o1;
}

extern "C" void kernel_launch(void* const* d_in, const int* in_sizes, int n_in,
                              void* d_out, int out_size, void* d_ws, size_t ws_size,
                              hipStream_t stream) {
  const float* x      = (const float*)d_in[0];
  const float* rw     = (const float*)d_in[1];
  const float* w_gate = (const float*)d_in[2];
  const float* w_up   = (const float*)d_in[3];
  const float* w_down = (const float*)d_in[4];
  const float* sw_g   = (const float*)d_in[5];
  const float* sw_u   = (const float*)d_in[6];
  const float* sw_d   = (const float*)d_in[7];
  float* out_final  = (float*)d_out;                      // [T][H]
  float* out_logits = out_final + (size_t)T_TOK * HDIM;   // [T][E]

  char* ws = (char*)d_ws;
  int*   selk     = (int*)(ws + 0);
  float* cwk      = (float*)(ws + 8192);
  int*   rowidx   = (int*)(ws + 16384);
  int*   tokrow   = (int*)(ws + 24576);
  float* rowwgt   = (float*)(ws + 40960);
  int*   tile_tab = (int*)(ws + 57344);
  size_t off = 65536;
  unsigned short* xg  = (unsigned short*)(ws + off);  off += (size_t)ROWS_ALL * HDIM * 2;
  unsigned short* hg  = (unsigned short*)(ws + off);  off += (size_t)ROW_CAP * IDIM * 2;
  unsigned short* hsh = (unsigned short*)(ws + off);  off += (size_t)T_TOK * ISH * 2;
  float* ydn          = (float*)(ws + off);           off += (size_t)ROW_CAP * HDIM * 4;
  unsigned short* wgub  = (unsigned short*)(ws + off);                // [8][2*1408][2048] bf16
  unsigned short* swgub = wgub + (size_t)NEXP * 2 * IDIM * HDIM;      // [2*2816][2048] bf16

  router_kernel<<<T_TOK, 256, 0, stream>>>(x, rw, out_logits, selk, cwk);
  plan_kernel<<<1, 512, 0, stream>>>(selk, cwk, rowidx, tokrow, rowwgt, tile_tab);

  // prep: gather (4096 blocks) + gate/up interleave-cvt (28160 blocks)
  prep_kernel<<<ROWS_ALL + 28160, 256, 0, stream>>>(
      x, tokrow, xg, w_gate, w_up, sw_g, sw_u, wgub, swgub);

  gu_kernel<<<880, 512, 0, stream>>>(xg, wgub, swgub, rowwgt, tile_tab, hg, hsh);

  dn_kernel<<<1024, 512, 0, stream>>>(hg, hsh, w_down, sw_d, tile_tab, ydn, out_final);
  combine_kernel<<<T_TOK, 256, 0, stream>>>(ydn, rowidx, out_final);
}

// Round 16
// 259.650 us; speedup vs baseline: 1.1208x; 1.1208x over previous
//
#include <hip/hip_runtime.h>
#include <hip/hip_bf16.h>
#include <math.h>

#define T_TOK 1024
#define HDIM  2048
#define NEXP  8
#define IDIM  1408
#define ISH   2816
#define ROW_CAP 3072
#define ROWS_ALL 4096
#define MOE_TILES 24
#define NT_TOT 32
#define ATILE (128*64)
#define GU_BLKS 880
#define CVT2_MOE 5632      // 8*2048*1408 / 4096
#define CVT2_ALL 7040      // + 2048*2816 / 4096

typedef __attribute__((ext_vector_type(8))) short bf16x8;
typedef __attribute__((ext_vector_type(4))) float f32x4;

static __device__ __forceinline__ unsigned short f2bf(float f) {
  __hip_bfloat16 h = __float2bfloat16(f);   // RTNE
  return __builtin_bit_cast(unsigned short, h);
}

#define PIPE_WAIT(N) do { \
    asm volatile("s_waitcnt vmcnt(" #N ")" ::: "memory"); \
    __builtin_amdgcn_s_barrier(); \
    __builtin_amdgcn_sched_barrier(0); \
  } while (0)

#define RAW_BAR() do { \
    __builtin_amdgcn_s_barrier(); \
    __builtin_amdgcn_sched_barrier(0); \
  } while (0)

// ---------------- router ----------------
__global__ __launch_bounds__(256) void router_kernel(
    const float* __restrict__ x, const float* __restrict__ rw,
    float* __restrict__ logits_out, int* __restrict__ selk, float* __restrict__ cwk)
{
  int t = blockIdx.x;
  int tid = threadIdx.x;
  float part[NEXP];
  const float* xr = x + (size_t)t * HDIM + tid * 8;
  float4 xa = *reinterpret_cast<const float4*>(xr);
  float4 xb = *reinterpret_cast<const float4*>(xr + 4);
  for (int e = 0; e < NEXP; ++e) {
    const float* wp = rw + (size_t)e * HDIM + tid * 8;
    float4 wa = *reinterpret_cast<const float4*>(wp);
    float4 wb = *reinterpret_cast<const float4*>(wp + 4);
    part[e] = xa.x*wa.x + xa.y*wa.y + xa.z*wa.z + xa.w*wa.w
            + xb.x*wb.x + xb.y*wb.y + xb.z*wb.z + xb.w*wb.w;
  }
  for (int e = 0; e < NEXP; ++e)
    for (int off = 32; off; off >>= 1)
      part[e] += __shfl_xor(part[e], off, 64);
  __shared__ float sums[4][NEXP];
  int wid = tid >> 6, lane = tid & 63;
  if (lane == 0) for (int e = 0; e < NEXP; ++e) sums[wid][e] = part[e];
  __syncthreads();
  if (tid == 0) {
    float lg[NEXP];
    for (int e = 0; e < NEXP; ++e) lg[e] = sums[0][e] + sums[1][e] + sums[2][e] + sums[3][e];
    float mx = lg[0];
    for (int e = 1; e < NEXP; ++e) mx = fmaxf(mx, lg[e]);
    float p[NEXP], s = 0.f;
    for (int e = 0; e < NEXP; ++e) { p[e] = expf(lg[e] - mx); s += p[e]; }
    for (int e = 0; e < NEXP; ++e) p[e] /= s;
    int i1 = 0;
    for (int e = 1; e < NEXP; ++e) if (lg[e] > lg[i1]) i1 = e;
    int i2 = -1;
    for (int e = 0; e < NEXP; ++e) { if (e == i1) continue; if (i2 < 0 || lg[e] > lg[i2]) i2 = e; }
    float denom = p[i1] + p[i2] + 1e-6f;
    selk[t*2] = i1; selk[t*2+1] = i2;
    cwk[t*2] = p[i1] / denom; cwk[t*2+1] = p[i2] / denom;
    for (int e = 0; e < NEXP; ++e) logits_out[t * NEXP + e] = lg[e];
  }
}

// ---------------- plan ----------------
__global__ __launch_bounds__(512) void plan_kernel(
    const int* __restrict__ selk, const float* __restrict__ cwk,
    int* __restrict__ rowidx, int* __restrict__ tok_of_row,
    float* __restrict__ rowwgt, int* __restrict__ tile_tab)
{
  __shared__ int cnt[NEXP];
  __shared__ int seg[NEXP];
  int tid = threadIdx.x;
  int w = tid >> 6, lane = tid & 63;
  for (int i = tid; i < ROW_CAP; i += 512) { tok_of_row[i] = -1; rowwgt[i] = 0.f; }
  for (int i = tid; i < T_TOK; i += 512) { tok_of_row[ROW_CAP + i] = i; rowwgt[ROW_CAP + i] = 1.f; }
  int total = 0;
  for (int base = 0; base < 2 * T_TOK; base += 64) {
    unsigned long long m = __ballot(selk[base + lane] == w);
    total += __popcll(m);
  }
  if (lane == 0) cnt[w] = total;
  __syncthreads();
  if (tid == 0) {
    int s = 0;
    for (int e = 0; e < NEXP; ++e) { seg[e] = s; s += (cnt[e] + 127) & ~127; }
  }
  __syncthreads();
  int run = seg[w];
  for (int base = 0; base < 2 * T_TOK; base += 64) {
    int i = base + lane;
    bool f = selk[i] == w;
    unsigned long long m = __ballot(f);
    if (f) {
      int r = run + __popcll(m & ((1ull << lane) - 1ull));
      rowidx[i] = r;
      tok_of_row[r] = i >> 1;
      rowwgt[r] = cwk[i];
    }
    run += __popcll(m);
  }
  __syncthreads();
  if (tid < NT_TOT) {
    int e = -1, valid = 0;
    if (tid < MOE_TILES) {
      int base = tid * 128;
      for (int k = 0; k < NEXP; ++k) {
        int s0 = seg[k], s1 = s0 + ((cnt[k] + 127) & ~127);
        if (base >= s0 && base < s1) {
          e = k;
          valid = cnt[k] - (base - s0);
          if (valid > 128) valid = 128;
          if (valid < 0) valid = 0;
        }
      }
    } else { e = 0; valid = 128; }
    tile_tab[tid*2] = e;
    tile_tab[tid*2+1] = valid;
  }
}

// ---- cvt one 2048-float row, write bf16 to dst row ----
static __device__ __forceinline__ void cvt_row(
    const float* __restrict__ src, unsigned short* __restrict__ dst, int tid)
{
  size_t idx = (size_t)tid * 8;
  float4 va = *reinterpret_cast<const float4*>(src + idx);
  float4 vb = *reinterpret_cast<const float4*>(src + idx + 4);
  union { unsigned short us[8]; uint4 q; } p;
  p.us[0]=f2bf(va.x); p.us[1]=f2bf(va.y); p.us[2]=f2bf(va.z); p.us[3]=f2bf(va.w);
  p.us[4]=f2bf(vb.x); p.us[5]=f2bf(vb.y); p.us[6]=f2bf(vb.z); p.us[7]=f2bf(vb.w);
  *reinterpret_cast<uint4*>(dst + idx) = p.q;
}

// ---------------- prep: gather (blocks 0..4095) + gate/up interleave-cvt (rest) ----------------
__global__ __launch_bounds__(256) void prep_kernel(
    const float* __restrict__ x, const int* __restrict__ tok_of_row,
    unsigned short* __restrict__ xg,
    const float* __restrict__ wg, const float* __restrict__ wu,
    const float* __restrict__ sg, const float* __restrict__ su,
    unsigned short* __restrict__ dmoe, unsigned short* __restrict__ dsh)
{
  int blk = blockIdx.x;
  int tid = threadIdx.x;
  if (blk < ROWS_ALL) {
    int tok = tok_of_row[blk];
    unsigned short* dst = xg + (size_t)blk * HDIM + tid * 8;
    union { unsigned short us[8]; uint4 q; } p;
    if (tok < 0) {
      p.q = uint4{0, 0, 0, 0};
    } else {
      const float* src = x + (size_t)tok * HDIM + tid * 8;
      float4 a = *reinterpret_cast<const float4*>(src);
      float4 b = *reinterpret_cast<const float4*>(src + 4);
      p.us[0]=f2bf(a.x); p.us[1]=f2bf(a.y); p.us[2]=f2bf(a.z); p.us[3]=f2bf(a.w);
      p.us[4]=f2bf(b.x); p.us[5]=f2bf(b.y); p.us[6]=f2bf(b.z); p.us[7]=f2bf(b.w);
    }
    *reinterpret_cast<uint4*>(dst) = p.q;
    return;
  }
  int b = blk - ROWS_ALL;
  const float* src; unsigned short* dst; size_t drow;
  if (b < NEXP * IDIM) {
    int e = b / IDIM, i = b - e * IDIM;
    src = wg + (size_t)b * HDIM; dst = dmoe;
    drow = (size_t)e * 2 * IDIM + ((i >> 4) << 5) + (i & 15);
  } else if (b < 2 * NEXP * IDIM) {
    int bb = b - NEXP * IDIM;
    int e = bb / IDIM, i = bb - e * IDIM;
    src = wu + (size_t)bb * HDIM; dst = dmoe;
    drow = (size_t)e * 2 * IDIM + ((i >> 4) << 5) + 16 + (i & 15);
  } else if (b < 2 * NEXP * IDIM + ISH) {
    int i = b - 2 * NEXP * IDIM;
    src = sg + (size_t)i * HDIM; dst = dsh;
    drow = ((size_t)(i >> 4) << 5) + (i & 15);
  } else {
    int i = b - 2 * NEXP * IDIM - ISH;
    src = su + (size_t)i * HDIM; dst = dsh;
    drow = ((size_t)(i >> 4) << 5) + 16 + (i & 15);
  }
  cvt_row(src, dst + drow * HDIM, tid);
}

// ---- tile stage: 128x64 bf16 via global_load_lds, 8 waves, XOR-8 source swizzle ----
static __device__ __forceinline__ void stage_t(
    const unsigned short* __restrict__ base, size_t ld, int k0,
    unsigned short* Ls, int wid, int lane)
{
  #pragma unroll
  for (int j = 0; j < 2; ++j) {
    int row = j * 64 + wid * 8 + (lane >> 3);
    int col = ((lane & 7) ^ (row & 7)) << 3;
    const unsigned short* src = base + (size_t)row * ld + k0 + col;
    unsigned short* dst = &Ls[(j * 64 + wid * 8) * 64];   // wave-uniform
    __builtin_amdgcn_global_load_lds(
        (const __attribute__((address_space(1))) void*)src,
        (__attribute__((address_space(3))) void*)dst, 16, 0, 0);
  }
}

// ---------------- gate+up SwiGLU GEMM (blocks 0..879) + down-weight cvt (rest) ----------------
__global__ __launch_bounds__(512) void gu_cvt_kernel(
    const unsigned short* __restrict__ xg,
    const unsigned short* __restrict__ wgub, const unsigned short* __restrict__ swgub,
    const float* __restrict__ rowwgt, const int* __restrict__ tile_tab,
    unsigned short* __restrict__ hg, unsigned short* __restrict__ hsh,
    const float* __restrict__ w_down, const float* __restrict__ sw_down,
    unsigned short* __restrict__ wdb, unsigned short* __restrict__ swdb)
{
  int bid0 = blockIdx.x;
  if (bid0 >= GU_BLKS) {
    // ---- cvt2 role: one 4096-float chunk per block (512 thr x 8) ----
    int b = bid0 - GU_BLKS;
    const float* s; unsigned short* d; size_t off;
    if (b < CVT2_MOE) { s = w_down; d = wdb; off = (size_t)b * 4096; }
    else { s = sw_down; d = swdb; off = (size_t)(b - CVT2_MOE) * 4096; }
    size_t idx = off + (size_t)threadIdx.x * 8;
    float4 va = *reinterpret_cast<const float4*>(s + idx);
    float4 vb = *reinterpret_cast<const float4*>(s + idx + 4);
    union { unsigned short us[8]; uint4 q; } p;
    p.us[0]=f2bf(va.x); p.us[1]=f2bf(va.y); p.us[2]=f2bf(va.z); p.us[3]=f2bf(va.w);
    p.us[4]=f2bf(vb.x); p.us[5]=f2bf(vb.y); p.us[6]=f2bf(vb.z); p.us[7]=f2bf(vb.w);
    *reinterpret_cast<uint4*>(d + idx) = p.q;
    return;
  }

  // ---- GEMM role: packed linear grid 880 = 8*110, mt-fastest + XCD chunk swizzle ----
  int lb = (bid0 & 7) * 110 + (bid0 >> 3);
  int mt, nt;
  if (lb < MOE_TILES * 22) { mt = lb % MOE_TILES; nt = lb / MOE_TILES; }
  else { int s = lb - MOE_TILES * 22; mt = MOE_TILES + (s & 7); nt = s >> 3; }

  int e = tile_tab[mt*2], valid = tile_tab[mt*2+1];
  if (valid <= 0) return;
  bool sh = mt >= MOE_TILES;
  int m0 = mt * 128;
  const unsigned short* wb; unsigned short* hout; int ldo;
  if (sh) { wb = swgub; hout = hsh + (size_t)(m0 - ROW_CAP) * ISH; ldo = ISH; }
  else {
    wb = wgub + (size_t)e * 2 * IDIM * HDIM;
    hout = hg + (size_t)m0 * IDIM; ldo = IDIM;
  }

  __shared__ unsigned short As[2 * ATILE];   // 32 KB
  __shared__ unsigned short Bs[2 * ATILE];   // 32 KB

  int tid = threadIdx.x, wid = tid >> 6, lane = tid & 63;
  int wr = wid >> 2, wc = wid & 3;
  int fr = lane & 15, fq = lane >> 4, fq8 = fq << 3;

  f32x4 acc[4][2] = {{}};                   // [m][0]=gate, [m][1]=up

  const unsigned short* abase = xg + (size_t)m0 * HDIM;
  const unsigned short* bbase = wb + (size_t)(nt * 128) * HDIM;

  stage_t(abase, HDIM, 0, As, wid, lane);
  stage_t(bbase, HDIM, 0, Bs, wid, lane);

  const int NK = HDIM / 64;   // 32
  for (int t = 0; t < NK; ++t) {
    int cur = t & 1;
    if (t + 1 < NK) {
      stage_t(abase, HDIM, (t + 1) * 64, As + (cur ^ 1) * ATILE, wid, lane);
      stage_t(bbase, HDIM, (t + 1) * 64, Bs + (cur ^ 1) * ATILE, wid, lane);
      PIPE_WAIT(4);
    } else {
      PIPE_WAIT(0);
    }
    const unsigned short* Ab = As + cur * ATILE;
    const unsigned short* Bb = Bs + cur * ATILE;
    #pragma unroll
    for (int kk = 0; kk < 64; kk += 32) {
      bf16x8 a[4], b[2];
      #pragma unroll
      for (int m = 0; m < 4; ++m) {
        int row = wr * 64 + m * 16 + fr;
        a[m] = *reinterpret_cast<const bf16x8*>(&Ab[row * 64 + ((kk + fq8) ^ ((row & 7) << 3))]);
      }
      #pragma unroll
      for (int n = 0; n < 2; ++n) {
        int brow = wc * 32 + n * 16 + fr;
        b[n] = *reinterpret_cast<const bf16x8*>(&Bb[brow * 64 + ((kk + fq8) ^ ((brow & 7) << 3))]);
      }
      #pragma unroll
      for (int m = 0; m < 4; ++m)
        #pragma unroll
        for (int n = 0; n < 2; ++n)
          acc[m][n] = __builtin_amdgcn_mfma_f32_16x16x32_bf16(a[m], b[n], acc[m][n], 0, 0, 0);
    }
    RAW_BAR();
  }

  int icol = nt * 64 + wc * 16 + fr;
  #pragma unroll
  for (int m = 0; m < 4; ++m)
    #pragma unroll
    for (int j = 0; j < 4; ++j) {
      int grow = wr * 64 + m * 16 + fq * 4 + j;
      float wv = rowwgt[m0 + grow];
      float g = acc[m][0][j], u = acc[m][1][j];
      float hv = g / (1.f + __expf(-g)) * u * wv;
      hout[(size_t)grow * ldo + icol] = f2bf(hv);
    }
}

// ---------------- down-proj GEMM: bf16 B, dbuf + counted vmcnt (R14-proven) ----------------
__global__ __launch_bounds__(512) void dn_kernel(
    const unsigned short* __restrict__ hg, const unsigned short* __restrict__ hsh,
    const unsigned short* __restrict__ wdb, const unsigned short* __restrict__ swdb,
    const int* __restrict__ tile_tab,
    float* __restrict__ ydn, float* __restrict__ outf)
{
  // packed linear grid 512 = 8*64, mt-fastest + XCD chunk swizzle
  int bid = blockIdx.x;
  int lb = (bid & 7) * 64 + (bid >> 3);
  int mt, nt;
  if (lb < MOE_TILES * 16) { mt = lb % MOE_TILES; nt = lb / MOE_TILES; }
  else { int s = lb - MOE_TILES * 16; mt = MOE_TILES + (s & 7); nt = s >> 3; }

  int e = tile_tab[mt*2], valid = tile_tab[mt*2+1];
  if (valid <= 0) return;
  bool sh = mt >= MOE_TILES;
  int m0 = mt * 128, n0 = nt * 128;
  const unsigned short* abase; const unsigned short* bbase; int K; float* obase;
  if (sh) { abase = hsh + (size_t)(m0 - ROW_CAP) * ISH; K = ISH; bbase = swdb; obase = outf + (size_t)(m0 - ROW_CAP) * HDIM; }
  else { abase = hg + (size_t)m0 * IDIM; K = IDIM; bbase = wdb + (size_t)e * HDIM * IDIM; obase = ydn + (size_t)m0 * HDIM; }

  __shared__ unsigned short As[2 * ATILE];   // 32 KB
  __shared__ unsigned short Bs[2 * ATILE];   // 32 KB

  int tid = threadIdx.x, wid = tid >> 6, lane = tid & 63;
  int wr = wid >> 2, wc = wid & 3;
  int fr = lane & 15, fq = lane >> 4, fq8 = fq << 3;

  f32x4 acc[4][2] = {{}};

  const unsigned short* bb = bbase + (size_t)n0 * K;

  stage_t(abase, K, 0, As, wid, lane);
  stage_t(bb,    K, 0, Bs, wid, lane);

  const int NK = K / 64;   // 22 or 44
  for (int t = 0; t < NK; ++t) {
    int cur = t & 1;
    if (t + 1 < NK) {
      stage_t(abase, K, (t + 1) * 64, As + (cur ^ 1) * ATILE, wid, lane);
      stage_t(bb,    K, (t + 1) * 64, Bs + (cur ^ 1) * ATILE, wid, lane);
      PIPE_WAIT(4);
    } else {
      PIPE_WAIT(0);
    }
    const unsigned short* Ab = As + cur * ATILE;
    const unsigned short* Bb = Bs + cur * ATILE;
    #pragma unroll
    for (int kk = 0; kk < 64; kk += 32) {
      bf16x8 a[4], b[2];
      #pragma unroll
      for (int m = 0; m < 4; ++m) {
        int row = wr * 64 + m * 16 + fr;
        a[m] = *reinterpret_cast<const bf16x8*>(&Ab[row * 64 + ((kk + fq8) ^ ((row & 7) << 3))]);
      }
      #pragma unroll
      for (int n = 0; n < 2; ++n) {
        int brow = wc * 32 + n * 16 + fr;
        b[n] = *reinterpret_cast<const bf16x8*>(&Bb[brow * 64 + ((kk + fq8) ^ ((brow & 7) << 3))]);
      }
      #pragma unroll
      for (int m = 0; m < 4; ++m)
        #pragma unroll
        for (int n = 0; n < 2; ++n)
          acc[m][n] = __builtin_amdgcn_mfma_f32_16x16x32_bf16(a[m], b[n], acc[m][n], 0, 0, 0);
    }
    RAW_BAR();
  }
  #pragma unroll
  for (int m = 0; m < 4; ++m)
    #pragma unroll
    for (int j = 0; j < 4; ++j) {
      int grow = wr * 64 + m * 16 + fq * 4 + j;
      #pragma unroll
      for (int n = 0; n < 2; ++n)
        obase[(size_t)grow * HDIM + n0 + wc * 32 + n * 16 + fr] = acc[m][n][j];
    }
}

// ---------------- combine ----------------
__global__ __launch_bounds__(256) void combine_kernel(
    const float* __restrict__ ydn, const int* __restrict__ rowidx,
    float* __restrict__ outf)
{
  int t = blockIdx.x;
  int c = threadIdx.x * 8;
  int r0 = rowidx[t*2], r1 = rowidx[t*2+1];
  const float4* a0 = reinterpret_cast<const float4*>(ydn + (size_t)r0 * HDIM + c);
  const float4* a1 = reinterpret_cast<const float4*>(ydn + (size_t)r1 * HDIM + c);
  float4* o = reinterpret_cast<float4*>(outf + (size_t)t * HDIM + c);
  float4 x0 = a0[0], x1 = a0[1], y0 = a1[0], y1 = a1[1];
  float4 o0 = o[0], o1 = o[1];
  o0.x += x0.x + y0.x; o0.y += x0.y + y0.y; o0.z += x0.z + y0.z; o0.w += x0.w + y0.w;
  o1.x += x1.x + y1.x; o1.y += x1.y + y1.y; o1.z += x1.z + y1.z; o1.w += x1.w + y1.w;
  o[0] = o0; o[1] = o1;
}

extern "C" void kernel_launch(void* const* d_in, const int* in_sizes, int n_in,
                              void* d_out, int out_size, void* d_ws, size_t ws_size,
                              hipStream_t stream) {
  const float* x      = (const float*)d_in[0];
  const float* rw     = (const float*)d_in[1];
  const float* w_gate = (const float*)d_in[2];
  const float* w_up   = (const float*)d_in[3];
  const float* w_down = (const float*)d_in[4];
  const float* sw_g   = (const float*)d_in[5];
  const float* sw_u   = (const float*)d_in[6];
  const float* sw_d   = (const float*)d_in[7];
  float* out_final  = (float*)d_out;                      // [T][H]
  float* out_logits = out_final + (size_t)T_TOK * HDIM;   // [T][E]

  char* ws = (char*)d_ws;
  int*   selk     = (int*)(ws + 0);
  float* cwk      = (float*)(ws + 8192);
  int*   rowidx   = (int*)(ws + 16384);
  int*   tokrow   = (int*)(ws + 24576);
  float* rowwgt   = (float*)(ws + 40960);
  int*   tile_tab = (int*)(ws + 57344);
  size_t off = 65536;
  unsigned short* xg  = (unsigned short*)(ws + off);  off += (size_t)ROWS_ALL * HDIM * 2;   // 16.8 MB
  unsigned short* hg  = (unsigned short*)(ws + off);  off += (size_t)ROW_CAP * IDIM * 2;    // 8.65 MB
  unsigned short* hsh = (unsigned short*)(ws + off);  off += (size_t)T_TOK * ISH * 2;       // 5.77 MB
  float* ydn          = (float*)(ws + off);           off += (size_t)ROW_CAP * HDIM * 4;    // 25.2 MB
  unsigned short* wgub  = (unsigned short*)(ws + off); off += (size_t)NEXP * 2 * IDIM * HDIM * 2; // 92.3 MB
  unsigned short* swgub = (unsigned short*)(ws + off); off += (size_t)2 * ISH * HDIM * 2;         // 23.1 MB
  unsigned short* wdb   = (unsigned short*)(ws + off); off += (size_t)NEXP * HDIM * IDIM * 2;     // 46.2 MB
  unsigned short* swdb  = (unsigned short*)(ws + off);                                            // 11.5 MB

  router_kernel<<<T_TOK, 256, 0, stream>>>(x, rw, out_logits, selk, cwk);
  plan_kernel<<<1, 512, 0, stream>>>(selk, cwk, rowidx, tokrow, rowwgt, tile_tab);

  // prep: gather (4096 blocks) + gate/up interleave-cvt (28160 blocks)
  prep_kernel<<<ROWS_ALL + 28160, 256, 0, stream>>>(
      x, tokrow, xg, w_gate, w_up, sw_g, sw_u, wgub, swgub);

  // gu GEMM (880 blocks) + down-weight cvt (7040 blocks) fused in one launch
  gu_cvt_kernel<<<GU_BLKS + CVT2_ALL, 512, 0, stream>>>(
      xg, wgub, swgub, rowwgt, tile_tab, hg, hsh, w_down, sw_d, wdb, swdb);

  dn_kernel<<<512, 512, 0, stream>>>(hg, hsh, wdb, swdb, tile_tab, ydn, out_final);
  combine_kernel<<<T_TOK, 256, 0, stream>>>(ydn, rowidx, out_final);
}

// Round 17
// 256.065 us; speedup vs baseline: 1.1365x; 1.0140x over previous
//
#include <hip/hip_runtime.h>
#include <hip/hip_bf16.h>
#include <math.h>

#define T_TOK 1024
#define HDIM  2048
#define NEXP  8
#define IDIM  1408
#define ISH   2816
#define ROW_CAP 3072
#define ROWS_ALL 4096
#define MOE_TILES 24
#define NT_TOT 32
#define ATILE (128*64)
#define GU_BLKS 880
#define CVT2_MOE 5632      // 8*2048*1408 / 4096
#define CVT2_ALL 7040      // + 2048*2816 / 4096

typedef __attribute__((ext_vector_type(8))) short bf16x8;
typedef __attribute__((ext_vector_type(4))) float f32x4;

static __device__ __forceinline__ unsigned short f2bf(float f) {
  __hip_bfloat16 h = __float2bfloat16(f);   // RTNE
  return __builtin_bit_cast(unsigned short, h);
}

#define PIPE_WAIT(N) do { \
    asm volatile("s_waitcnt vmcnt(" #N ")" ::: "memory"); \
    __builtin_amdgcn_s_barrier(); \
    __builtin_amdgcn_sched_barrier(0); \
  } while (0)

#define RAW_BAR() do { \
    __builtin_amdgcn_s_barrier(); \
    __builtin_amdgcn_sched_barrier(0); \
  } while (0)

// ---------------- router ----------------
__global__ __launch_bounds__(256) void router_kernel(
    const float* __restrict__ x, const float* __restrict__ rw,
    float* __restrict__ logits_out, int* __restrict__ selk, float* __restrict__ cwk)
{
  int t = blockIdx.x;
  int tid = threadIdx.x;
  float part[NEXP];
  const float* xr = x + (size_t)t * HDIM + tid * 8;
  float4 xa = *reinterpret_cast<const float4*>(xr);
  float4 xb = *reinterpret_cast<const float4*>(xr + 4);
  for (int e = 0; e < NEXP; ++e) {
    const float* wp = rw + (size_t)e * HDIM + tid * 8;
    float4 wa = *reinterpret_cast<const float4*>(wp);
    float4 wb = *reinterpret_cast<const float4*>(wp + 4);
    part[e] = xa.x*wa.x + xa.y*wa.y + xa.z*wa.z + xa.w*wa.w
            + xb.x*wb.x + xb.y*wb.y + xb.z*wb.z + xb.w*wb.w;
  }
  for (int e = 0; e < NEXP; ++e)
    for (int off = 32; off; off >>= 1)
      part[e] += __shfl_xor(part[e], off, 64);
  __shared__ float sums[4][NEXP];
  int wid = tid >> 6, lane = tid & 63;
  if (lane == 0) for (int e = 0; e < NEXP; ++e) sums[wid][e] = part[e];
  __syncthreads();
  if (tid == 0) {
    float lg[NEXP];
    for (int e = 0; e < NEXP; ++e) lg[e] = sums[0][e] + sums[1][e] + sums[2][e] + sums[3][e];
    float mx = lg[0];
    for (int e = 1; e < NEXP; ++e) mx = fmaxf(mx, lg[e]);
    float p[NEXP], s = 0.f;
    for (int e = 0; e < NEXP; ++e) { p[e] = expf(lg[e] - mx); s += p[e]; }
    for (int e = 0; e < NEXP; ++e) p[e] /= s;
    int i1 = 0;
    for (int e = 1; e < NEXP; ++e) if (lg[e] > lg[i1]) i1 = e;
    int i2 = -1;
    for (int e = 0; e < NEXP; ++e) { if (e == i1) continue; if (i2 < 0 || lg[e] > lg[i2]) i2 = e; }
    float denom = p[i1] + p[i2] + 1e-6f;
    selk[t*2] = i1; selk[t*2+1] = i2;
    cwk[t*2] = p[i1] / denom; cwk[t*2+1] = p[i2] / denom;
    for (int e = 0; e < NEXP; ++e) logits_out[t * NEXP + e] = lg[e];
  }
}

// ---------------- plan ----------------
__global__ __launch_bounds__(512) void plan_kernel(
    const int* __restrict__ selk, const float* __restrict__ cwk,
    int* __restrict__ rowidx, int* __restrict__ tok_of_row,
    float* __restrict__ rowwgt, int* __restrict__ tile_tab)
{
  __shared__ int cnt[NEXP];
  __shared__ int seg[NEXP];
  int tid = threadIdx.x;
  int w = tid >> 6, lane = tid & 63;
  for (int i = tid; i < ROW_CAP; i += 512) { tok_of_row[i] = -1; rowwgt[i] = 0.f; }
  for (int i = tid; i < T_TOK; i += 512) { tok_of_row[ROW_CAP + i] = i; rowwgt[ROW_CAP + i] = 1.f; }
  int total = 0;
  for (int base = 0; base < 2 * T_TOK; base += 64) {
    unsigned long long m = __ballot(selk[base + lane] == w);
    total += __popcll(m);
  }
  if (lane == 0) cnt[w] = total;
  __syncthreads();
  if (tid == 0) {
    int s = 0;
    for (int e = 0; e < NEXP; ++e) { seg[e] = s; s += (cnt[e] + 127) & ~127; }
  }
  __syncthreads();
  int run = seg[w];
  for (int base = 0; base < 2 * T_TOK; base += 64) {
    int i = base + lane;
    bool f = selk[i] == w;
    unsigned long long m = __ballot(f);
    if (f) {
      int r = run + __popcll(m & ((1ull << lane) - 1ull));
      rowidx[i] = r;
      tok_of_row[r] = i >> 1;
      rowwgt[r] = cwk[i];
    }
    run += __popcll(m);
  }
  __syncthreads();
  if (tid < NT_TOT) {
    int e = -1, valid = 0;
    if (tid < MOE_TILES) {
      int base = tid * 128;
      for (int k = 0; k < NEXP; ++k) {
        int s0 = seg[k], s1 = s0 + ((cnt[k] + 127) & ~127);
        if (base >= s0 && base < s1) {
          e = k;
          valid = cnt[k] - (base - s0);
          if (valid > 128) valid = 128;
          if (valid < 0) valid = 0;
        }
      }
    } else { e = 0; valid = 128; }
    tile_tab[tid*2] = e;
    tile_tab[tid*2+1] = valid;
  }
}

// ---- cvt one 2048-float row, write bf16 to dst row ----
static __device__ __forceinline__ void cvt_row(
    const float* __restrict__ src, unsigned short* __restrict__ dst, int tid)
{
  size_t idx = (size_t)tid * 8;
  float4 va = *reinterpret_cast<const float4*>(src + idx);
  float4 vb = *reinterpret_cast<const float4*>(src + idx + 4);
  union { unsigned short us[8]; uint4 q; } p;
  p.us[0]=f2bf(va.x); p.us[1]=f2bf(va.y); p.us[2]=f2bf(va.z); p.us[3]=f2bf(va.w);
  p.us[4]=f2bf(vb.x); p.us[5]=f2bf(vb.y); p.us[6]=f2bf(vb.z); p.us[7]=f2bf(vb.w);
  *reinterpret_cast<uint4*>(dst + idx) = p.q;
}

// ---------------- prep: gather (blocks 0..4095) + gate/up interleave-cvt (rest) ----------------
__global__ __launch_bounds__(256) void prep_kernel(
    const float* __restrict__ x, const int* __restrict__ tok_of_row,
    unsigned short* __restrict__ xg,
    const float* __restrict__ wg, const float* __restrict__ wu,
    const float* __restrict__ sg, const float* __restrict__ su,
    unsigned short* __restrict__ dmoe, unsigned short* __restrict__ dsh)
{
  int blk = blockIdx.x;
  int tid = threadIdx.x;
  if (blk < ROWS_ALL) {
    int tok = tok_of_row[blk];
    unsigned short* dst = xg + (size_t)blk * HDIM + tid * 8;
    union { unsigned short us[8]; uint4 q; } p;
    if (tok < 0) {
      p.q = uint4{0, 0, 0, 0};
    } else {
      const float* src = x + (size_t)tok * HDIM + tid * 8;
      float4 a = *reinterpret_cast<const float4*>(src);
      float4 b = *reinterpret_cast<const float4*>(src + 4);
      p.us[0]=f2bf(a.x); p.us[1]=f2bf(a.y); p.us[2]=f2bf(a.z); p.us[3]=f2bf(a.w);
      p.us[4]=f2bf(b.x); p.us[5]=f2bf(b.y); p.us[6]=f2bf(b.z); p.us[7]=f2bf(b.w);
    }
    *reinterpret_cast<uint4*>(dst) = p.q;
    return;
  }
  int b = blk - ROWS_ALL;
  const float* src; unsigned short* dst; size_t drow;
  if (b < NEXP * IDIM) {
    int e = b / IDIM, i = b - e * IDIM;
    src = wg + (size_t)b * HDIM; dst = dmoe;
    drow = (size_t)e * 2 * IDIM + ((i >> 4) << 5) + (i & 15);
  } else if (b < 2 * NEXP * IDIM) {
    int bb = b - NEXP * IDIM;
    int e = bb / IDIM, i = bb - e * IDIM;
    src = wu + (size_t)bb * HDIM; dst = dmoe;
    drow = (size_t)e * 2 * IDIM + ((i >> 4) << 5) + 16 + (i & 15);
  } else if (b < 2 * NEXP * IDIM + ISH) {
    int i = b - 2 * NEXP * IDIM;
    src = sg + (size_t)i * HDIM; dst = dsh;
    drow = ((size_t)(i >> 4) << 5) + (i & 15);
  } else {
    int i = b - 2 * NEXP * IDIM - ISH;
    src = su + (size_t)i * HDIM; dst = dsh;
    drow = ((size_t)(i >> 4) << 5) + 16 + (i & 15);
  }
  cvt_row(src, dst + drow * HDIM, tid);
}

// ---- tile stage: 128x64 bf16 via global_load_lds, 8 waves, XOR-8 source swizzle ----
static __device__ __forceinline__ void stage_t(
    const unsigned short* __restrict__ base, size_t ld, int k0,
    unsigned short* Ls, int wid, int lane)
{
  #pragma unroll
  for (int j = 0; j < 2; ++j) {
    int row = j * 64 + wid * 8 + (lane >> 3);
    int col = ((lane & 7) ^ (row & 7)) << 3;
    const unsigned short* src = base + (size_t)row * ld + k0 + col;
    unsigned short* dst = &Ls[(j * 64 + wid * 8) * 64];   // wave-uniform
    __builtin_amdgcn_global_load_lds(
        (const __attribute__((address_space(1))) void*)src,
        (__attribute__((address_space(3))) void*)dst, 16, 0, 0);
  }
}

// ---------------- gate+up SwiGLU GEMM (blocks 0..879) + down-weight cvt (rest) ----------------
__global__ __launch_bounds__(512) void gu_cvt_kernel(
    const unsigned short* __restrict__ xg,
    const unsigned short* __restrict__ wgub, const unsigned short* __restrict__ swgub,
    const float* __restrict__ rowwgt, const int* __restrict__ tile_tab,
    unsigned short* __restrict__ hg, unsigned short* __restrict__ hsh,
    const float* __restrict__ w_down, const float* __restrict__ sw_down,
    unsigned short* __restrict__ wdb, unsigned short* __restrict__ swdb)
{
  int bid0 = blockIdx.x;
  if (bid0 >= GU_BLKS) {
    // ---- cvt2 role: one 4096-float chunk per block (512 thr x 8) ----
    int b = bid0 - GU_BLKS;
    const float* s; unsigned short* d; size_t off;
    if (b < CVT2_MOE) { s = w_down; d = wdb; off = (size_t)b * 4096; }
    else { s = sw_down; d = swdb; off = (size_t)(b - CVT2_MOE) * 4096; }
    size_t idx = off + (size_t)threadIdx.x * 8;
    float4 va = *reinterpret_cast<const float4*>(s + idx);
    float4 vb = *reinterpret_cast<const float4*>(s + idx + 4);
    union { unsigned short us[8]; uint4 q; } p;
    p.us[0]=f2bf(va.x); p.us[1]=f2bf(va.y); p.us[2]=f2bf(va.z); p.us[3]=f2bf(va.w);
    p.us[4]=f2bf(vb.x); p.us[5]=f2bf(vb.y); p.us[6]=f2bf(vb.z); p.us[7]=f2bf(vb.w);
    *reinterpret_cast<uint4*>(d + idx) = p.q;
    return;
  }

  // ---- GEMM role: packed linear grid 880 = 8*110, mt-fastest + XCD chunk swizzle ----
  int lb = (bid0 & 7) * 110 + (bid0 >> 3);
  int mt, nt;
  if (lb < MOE_TILES * 22) { mt = lb % MOE_TILES; nt = lb / MOE_TILES; }
  else { int s = lb - MOE_TILES * 22; mt = MOE_TILES + (s & 7); nt = s >> 3; }

  int e = tile_tab[mt*2], valid = tile_tab[mt*2+1];
  if (valid <= 0) return;
  bool sh = mt >= MOE_TILES;
  int m0 = mt * 128;
  const unsigned short* wb; unsigned short* hout; int ldo;
  if (sh) { wb = swgub; hout = hsh + (size_t)(m0 - ROW_CAP) * ISH; ldo = ISH; }
  else {
    wb = wgub + (size_t)e * 2 * IDIM * HDIM;
    hout = hg + (size_t)m0 * IDIM; ldo = IDIM;
  }

  __shared__ unsigned short As[2 * ATILE];   // 32 KB
  __shared__ unsigned short Bs[2 * ATILE];   // 32 KB

  int tid = threadIdx.x, wid = tid >> 6, lane = tid & 63;
  int wr = wid >> 2, wc = wid & 3;
  int fr = lane & 15, fq = lane >> 4, fq8 = fq << 3;

  f32x4 acc[4][2] = {{}};                   // [m][0]=gate, [m][1]=up

  const unsigned short* abase = xg + (size_t)m0 * HDIM;
  const unsigned short* bbase = wb + (size_t)(nt * 128) * HDIM;

  stage_t(abase, HDIM, 0, As, wid, lane);
  stage_t(bbase, HDIM, 0, Bs, wid, lane);

  const int NK = HDIM / 64;   // 32
  for (int t = 0; t < NK; ++t) {
    int cur = t & 1;
    if (t + 1 < NK) {
      stage_t(abase, HDIM, (t + 1) * 64, As + (cur ^ 1) * ATILE, wid, lane);
      stage_t(bbase, HDIM, (t + 1) * 64, Bs + (cur ^ 1) * ATILE, wid, lane);
      PIPE_WAIT(4);
    } else {
      PIPE_WAIT(0);
    }
    const unsigned short* Ab = As + cur * ATILE;
    const unsigned short* Bb = Bs + cur * ATILE;
    #pragma unroll
    for (int kk = 0; kk < 64; kk += 32) {
      bf16x8 a[4], b[2];
      #pragma unroll
      for (int m = 0; m < 4; ++m) {
        int row = wr * 64 + m * 16 + fr;
        a[m] = *reinterpret_cast<const bf16x8*>(&Ab[row * 64 + ((kk + fq8) ^ ((row & 7) << 3))]);
      }
      #pragma unroll
      for (int n = 0; n < 2; ++n) {
        int brow = wc * 32 + n * 16 + fr;
        b[n] = *reinterpret_cast<const bf16x8*>(&Bb[brow * 64 + ((kk + fq8) ^ ((brow & 7) << 3))]);
      }
      #pragma unroll
      for (int m = 0; m < 4; ++m)
        #pragma unroll
        for (int n = 0; n < 2; ++n)
          acc[m][n] = __builtin_amdgcn_mfma_f32_16x16x32_bf16(a[m], b[n], acc[m][n], 0, 0, 0);
    }
    RAW_BAR();
  }

  int icol = nt * 64 + wc * 16 + fr;
  #pragma unroll
  for (int m = 0; m < 4; ++m)
    #pragma unroll
    for (int j = 0; j < 4; ++j) {
      int grow = wr * 64 + m * 16 + fq * 4 + j;
      float wv = rowwgt[m0 + grow];
      float g = acc[m][0][j], u = acc[m][1][j];
      float hv = g / (1.f + __expf(-g)) * u * wv;
      hout[(size_t)grow * ldo + icol] = f2bf(hv);
    }
}

// ---------------- down-proj GEMM: bf16 B, dbuf + counted vmcnt, atomic epilogue ----------------
__global__ __launch_bounds__(512) void dn_kernel(
    const unsigned short* __restrict__ hg, const unsigned short* __restrict__ hsh,
    const unsigned short* __restrict__ wdb, const unsigned short* __restrict__ swdb,
    const int* __restrict__ tile_tab, const int* __restrict__ tok_of_row,
    float* __restrict__ outf)
{
  // packed linear grid 512 = 8*64, mt-fastest + XCD chunk swizzle
  int bid = blockIdx.x;
  int lb = (bid & 7) * 64 + (bid >> 3);
  int mt, nt;
  if (lb < MOE_TILES * 16) { mt = lb % MOE_TILES; nt = lb / MOE_TILES; }
  else { int s = lb - MOE_TILES * 16; mt = MOE_TILES + (s & 7); nt = s >> 3; }

  int e = tile_tab[mt*2], valid = tile_tab[mt*2+1];
  if (valid <= 0) return;
  bool sh = mt >= MOE_TILES;
  int m0 = mt * 128, n0 = nt * 128;
  const unsigned short* abase; const unsigned short* bbase; int K;
  if (sh) { abase = hsh + (size_t)(m0 - ROW_CAP) * ISH; K = ISH; bbase = swdb; }
  else { abase = hg + (size_t)m0 * IDIM; K = IDIM; bbase = wdb + (size_t)e * HDIM * IDIM; }

  __shared__ unsigned short As[2 * ATILE];   // 32 KB
  __shared__ unsigned short Bs[2 * ATILE];   // 32 KB

  int tid = threadIdx.x, wid = tid >> 6, lane = tid & 63;
  int wr = wid >> 2, wc = wid & 3;
  int fr = lane & 15, fq = lane >> 4, fq8 = fq << 3;

  f32x4 acc[4][2] = {{}};

  const unsigned short* bb = bbase + (size_t)n0 * K;

  stage_t(abase, K, 0, As, wid, lane);
  stage_t(bb,    K, 0, Bs, wid, lane);

  const int NK = K / 64;   // 22 or 44
  for (int t = 0; t < NK; ++t) {
    int cur = t & 1;
    if (t + 1 < NK) {
      stage_t(abase, K, (t + 1) * 64, As + (cur ^ 1) * ATILE, wid, lane);
      stage_t(bb,    K, (t + 1) * 64, Bs + (cur ^ 1) * ATILE, wid, lane);
      PIPE_WAIT(4);
    } else {
      PIPE_WAIT(0);
    }
    const unsigned short* Ab = As + cur * ATILE;
    const unsigned short* Bb = Bs + cur * ATILE;
    #pragma unroll
    for (int kk = 0; kk < 64; kk += 32) {
      bf16x8 a[4], b[2];
      #pragma unroll
      for (int m = 0; m < 4; ++m) {
        int row = wr * 64 + m * 16 + fr;
        a[m] = *reinterpret_cast<const bf16x8*>(&Ab[row * 64 + ((kk + fq8) ^ ((row & 7) << 3))]);
      }
      #pragma unroll
      for (int n = 0; n < 2; ++n) {
        int brow = wc * 32 + n * 16 + fr;
        b[n] = *reinterpret_cast<const bf16x8*>(&Bb[brow * 64 + ((kk + fq8) ^ ((brow & 7) << 3))]);
      }
      #pragma unroll
      for (int m = 0; m < 4; ++m)
        #pragma unroll
        for (int n = 0; n < 2; ++n)
          acc[m][n] = __builtin_amdgcn_mfma_f32_16x16x32_bf16(a[m], b[n], acc[m][n], 0, 0, 0);
    }
    RAW_BAR();
  }
  #pragma unroll
  for (int m = 0; m < 4; ++m)
    #pragma unroll
    for (int j = 0; j < 4; ++j) {
      int grow = wr * 64 + m * 16 + fq * 4 + j;
      int tok = tok_of_row[m0 + grow];           // works for MoE and shared rows
      if (tok >= 0) {
        #pragma unroll
        for (int n = 0; n < 2; ++n)
          atomicAdd(outf + (size_t)tok * HDIM + n0 + wc * 32 + n * 16 + fr, acc[m][n][j]);
      }
    }
}

extern "C" void kernel_launch(void* const* d_in, const int* in_sizes, int n_in,
                              void* d_out, int out_size, void* d_ws, size_t ws_size,
                              hipStream_t stream) {
  const float* x      = (const float*)d_in[0];
  const float* rw     = (const float*)d_in[1];
  const float* w_gate = (const float*)d_in[2];
  const float* w_up   = (const float*)d_in[3];
  const float* w_down = (const float*)d_in[4];
  const float* sw_g   = (const float*)d_in[5];
  const float* sw_u   = (const float*)d_in[6];
  const float* sw_d   = (const float*)d_in[7];
  float* out_final  = (float*)d_out;                      // [T][H]
  float* out_logits = out_final + (size_t)T_TOK * HDIM;   // [T][E]

  char* ws = (char*)d_ws;
  int*   selk     = (int*)(ws + 0);
  float* cwk      = (float*)(ws + 8192);
  int*   rowidx   = (int*)(ws + 16384);
  int*   tokrow   = (int*)(ws + 24576);
  float* rowwgt   = (float*)(ws + 40960);
  int*   tile_tab = (int*)(ws + 57344);
  size_t off = 65536;
  unsigned short* xg  = (unsigned short*)(ws + off);  off += (size_t)ROWS_ALL * HDIM * 2;   // 16.8 MB
  unsigned short* hg  = (unsigned short*)(ws + off);  off += (size_t)ROW_CAP * IDIM * 2;    // 8.65 MB
  unsigned short* hsh = (unsigned short*)(ws + off);  off += (size_t)T_TOK * ISH * 2;       // 5.77 MB
  unsigned short* wgub  = (unsigned short*)(ws + off); off += (size_t)NEXP * 2 * IDIM * HDIM * 2; // 92.3 MB
  unsigned short* swgub = (unsigned short*)(ws + off); off += (size_t)2 * ISH * HDIM * 2;         // 23.1 MB
  unsigned short* wdb   = (unsigned short*)(ws + off); off += (size_t)NEXP * HDIM * IDIM * 2;     // 46.2 MB
  unsigned short* swdb  = (unsigned short*)(ws + off);                                            // 11.5 MB

  // zero the accumulation target (atomic epilogue adds into it)
  hipMemsetAsync(out_final, 0, (size_t)T_TOK * HDIM * sizeof(float), stream);

  router_kernel<<<T_TOK, 256, 0, stream>>>(x, rw, out_logits, selk, cwk);
  plan_kernel<<<1, 512, 0, stream>>>(selk, cwk, rowidx, tokrow, rowwgt, tile_tab);

  // prep: gather (4096 blocks) + gate/up interleave-cvt (28160 blocks)
  prep_kernel<<<ROWS_ALL + 28160, 256, 0, stream>>>(
      x, tokrow, xg, w_gate, w_up, sw_g, sw_u, wgub, swgub);

  // gu GEMM (880 blocks) + down-weight cvt (7040 blocks) fused in one launch
  gu_cvt_kernel<<<GU_BLKS + CVT2_ALL, 512, 0, stream>>>(
      xg, wgub, swgub, rowwgt, tile_tab, hg, hsh, w_down, sw_d, wdb, swdb);

  dn_kernel<<<512, 512, 0, stream>>>(hg, hsh, wdb, swdb, tile_tab, tokrow, out_final);
}